// Round 10
// baseline (37.651 us; speedup 1.0000x reference)
//
#include <hip/hip_runtime.h>
#include <cfloat>

#define NEG_INF_F (-1e30f)

constexpr int BB = 8, SS = 4096, HH = 1024;
constexpr int TOTAL = BB * SS;   // 32768 rows
constexpr int MAXLEN = 30;
constexpr int RPB = 256;         // topk rows per block
constexpr int BLK_PER_B = SS / RPB;          // 16
constexpr int TK_GRID = BB * BLK_PER_B;      // 128

// ---------------- Kernel 1: QA-head GEMV + masking (proven ~20.5 us) ---------
// NOTE: plain __launch_bounds__(256) only — adding a min-waves hint capped
// VGPRs (32-36) and serialized the 12 in-flight loads (R6/R8: 370 GB/s).
__global__ __launch_bounds__(256) void qa_logits_kernel(
    const float* __restrict__ X,     // (B*S, H)
    const float* __restrict__ mask,  // (B*S)
    const float* __restrict__ W,     // (H, 2) row-major
    const float* __restrict__ bqa,   // (2)
    float* __restrict__ out,         // [0,TOTAL): start, [TOTAL,2*TOTAL): end
    unsigned* __restrict__ cnt) {    // (BB) ticket counters for next kernel
  if (blockIdx.x == 0 && threadIdx.x < BB) cnt[threadIdx.x] = 0u;
  int row  = (int)((blockIdx.x * (size_t)blockDim.x + threadIdx.x) >> 6);
  int lane = threadIdx.x & 63;
  if (row >= TOTAL) return;
  const float* rp = X + (size_t)row * HH;
  float s0 = 0.f, s1 = 0.f;
#pragma unroll
  for (int k = 0; k < HH / 256; ++k) {
    int h = (k * 64 + lane) * 4;
    const float4 x   = *reinterpret_cast<const float4*>(rp + h);
    const float4 w01 = *reinterpret_cast<const float4*>(W + 2 * h);
    const float4 w23 = *reinterpret_cast<const float4*>(W + 2 * h + 4);
    s0 += x.x * w01.x + x.y * w01.z + x.z * w23.x + x.w * w23.z;
    s1 += x.x * w01.y + x.y * w01.w + x.z * w23.y + x.w * w23.w;
  }
#pragma unroll
  for (int off = 32; off > 0; off >>= 1) {
    s0 += __shfl_down(s0, off);
    s1 += __shfl_down(s1, off);
  }
  if (lane == 0) {
    float m = mask[row];
    float inv = 1.f - m;
    out[row]         = (s0 + bqa[0]) * m + inv * NEG_INF_F;
    out[TOTAL + row] = (s1 + bqa[1]) * m + inv * NEG_INF_F;
  }
}

// ---------- packed u64 key: (sortable-float << 32) | (~idx) ----------
// Higher key = higher value, then lower flat index (jax top_k tie-break).
// Scheme validated end-to-end in rounds 8-9 (passed).
__device__ __forceinline__ unsigned long long pack_key(float v, unsigned idx) {
  unsigned u = __float_as_uint(v);
  u = (u & 0x80000000u) ? ~u : (u | 0x80000000u);
  return ((unsigned long long)u << 32) | (unsigned long long)(0xFFFFFFFFu - idx);
}

// Sorted-descending 5-key insert, early exit (keys unique, 0 = sentinel).
__device__ __forceinline__ void k5_insert(unsigned long long k[5], unsigned long long nk) {
  if (nk <= k[4]) return;
  k[4] = nk;
  unsigned long long t;
  if (k[4] > k[3]) { t = k[3]; k[3] = k[4]; k[4] = t; }
  if (k[3] > k[2]) { t = k[2]; k[2] = k[3]; k[3] = t; }
  if (k[2] > k[1]) { t = k[1]; k[1] = k[2]; k[2] = t; }
  if (k[1] > k[0]) { t = k[0]; k[0] = k[1]; k[1] = t; }
}

// Wave-wide top-5 via 5 argmax rounds on u64 keys; result same in all lanes.
__device__ __forceinline__ void wave_top5_u64(unsigned long long k[5],
                                              unsigned long long r[5]) {
#pragma unroll
  for (int q = 0; q < 5; ++q) {
    unsigned long long m = k[0];
    if (k[1] > m) m = k[1];
    if (k[2] > m) m = k[2];
    if (k[3] > m) m = k[3];
    if (k[4] > m) m = k[4];
#pragma unroll
    for (int off = 1; off < 64; off <<= 1) {
      unsigned long long o = __shfl_xor(m, off);
      if (o > m) m = o;
    }
    r[q] = m;
#pragma unroll
    for (int p = 0; p < 5; ++p)
      if (k[p] == m) k[p] = 0ull;  // keys unique; invalidate winner
  }
}

// ---------------- Kernel 2: LDS-staged banded top-5, single dispatch --------
// 128 blocks x 256 threads; block = 256 consecutive rows of one batch.
// Coalesced float4 stage of st[256] + en[286] into LDS (loads OUT of the
// insert chain — R9's proven structure), scan, block merge, then agent-scope
// ticket (R7's proven mechanism): last block per batch merges 16x5=80 keys.
__global__ __launch_bounds__(RPB) void topk_kernel(
    const float* __restrict__ logits,      // gemv output (start then end)
    float* __restrict__ out,
    unsigned long long* __restrict__ ws,   // (TK_GRID, 5) block top-5 keys
    unsigned* __restrict__ cnt) {          // (BB), zeroed by gemv
  const int b  = blockIdx.x / BLK_PER_B;
  const int rb = blockIdx.x % BLK_PER_B;
  const int i0 = rb * RPB;
  const int t  = (int)threadIdx.x;
  const int lane = t & 63;
  const int w = t >> 6;

  __shared__ float s_st[RPB];
  __shared__ float s_en[RPB + 32];       // window tail (+pad)
  __shared__ unsigned long long sk[(RPB / 64) * 5];

  const float* st = logits + (size_t)b * SS + i0;
  const float* en = logits + (size_t)(BB + b) * SS + i0;
  const int n_en = min(SS - i0, RPB + MAXLEN - 1);   // floats of en to stage

  if (t < RPB / 4)
    *reinterpret_cast<float4*>(&s_st[t * 4]) =
        *reinterpret_cast<const float4*>(st + t * 4);
  else if (t >= 64 && t < 64 + (n_en + 3) / 4) {
    int r = t - 64;
    if (r * 4 + 4 <= n_en)
      *reinterpret_cast<float4*>(&s_en[r * 4]) =
          *reinterpret_cast<const float4*>(en + r * 4);
    else
      for (int c = r * 4; c < n_en; ++c) s_en[c] = en[c];
  }
  __syncthreads();

  unsigned long long k5[5] = {0, 0, 0, 0, 0};
  const int i = i0 + t;
  if (i >= 4) {
    float sv = s_st[t];
    unsigned base = (unsigned)(i * SS + i);
    int cap = n_en - t;  // #valid c (j = i+c < S)
#pragma unroll
    for (int c = 0; c < MAXLEN; ++c)
      if (c < cap) k5_insert(k5, pack_key(sv + s_en[t + c], base + c));
  } else if (i >= 1) {   // spans (1,1),(2,2),(3,3)
    k5_insert(k5, pack_key(s_st[t] + s_en[t], (unsigned)(i * SS + i)));
  }

  unsigned long long r5[5];
  wave_top5_u64(k5, r5);
  if (lane == 0) {
#pragma unroll
    for (int q = 0; q < 5; ++q) sk[w * 5 + q] = r5[q];
  }
  __syncthreads();

  if (w == 0) {  // wave 0: merge 4 waves * 5 = 20 keys -> block top-5
    unsigned long long m5[5] = {0, 0, 0, 0, 0};
    if (lane < (RPB / 64) * 5) m5[0] = sk[lane];
    unsigned long long f5[5];
    wave_top5_u64(m5, f5);

    // publish block result + ticket (mechanism proven in R7)
    unsigned old = 0;
    if (lane == 0) {
#pragma unroll
      for (int q = 0; q < 5; ++q)
        __hip_atomic_store(&ws[blockIdx.x * 5 + q], f5[q],
                           __ATOMIC_RELAXED, __HIP_MEMORY_SCOPE_AGENT);
      __threadfence();  // release: block result visible before ticket
      old = __hip_atomic_fetch_add(&cnt[b], 1u, __ATOMIC_RELAXED,
                                   __HIP_MEMORY_SCOPE_AGENT);
    }
    old = __shfl(old, 0);

    if (old == (unsigned)(BLK_PER_B - 1)) {  // last block of this batch
      __threadfence();                       // acquire
      const unsigned long long* src = ws + (size_t)b * BLK_PER_B * 5;  // 80 keys
      unsigned long long g5[5] = {0, 0, 0, 0, 0};
      g5[0] = __hip_atomic_load(&src[lane], __ATOMIC_RELAXED,
                                __HIP_MEMORY_SCOPE_AGENT);
      if (lane < BLK_PER_B * 5 - 64)
        g5[1] = __hip_atomic_load(&src[64 + lane], __ATOMIC_RELAXED,
                                  __HIP_MEMORY_SCOPE_AGENT);
      unsigned long long h5[5];
      wave_top5_u64(g5, h5);
      if (lane == 0) {
        float* ts = out + 2 * (size_t)TOTAL;  // top_start region
        float* te = ts + BB * 5;              // top_end region
#pragma unroll
        for (int q = 0; q < 5; ++q) {
          unsigned idx = 0xFFFFFFFFu - (unsigned)(h5[q] & 0xFFFFFFFFull);
          ts[b * 5 + q] = (float)(idx >> 12);       // idx / S  (S=4096)
          te[b * 5 + q] = (float)(idx & (SS - 1));  // idx % S
        }
      }
    }
  }
}

extern "C" void kernel_launch(void* const* d_in, const int* in_sizes, int n_in,
                              void* d_out, int out_size, void* d_ws, size_t ws_size,
                              hipStream_t stream) {
  const float* X    = (const float*)d_in[0];  // (B,S,H)
  const float* mask = (const float*)d_in[1];  // (B,S)
  const float* W    = (const float*)d_in[2];  // (H,2)
  const float* bqa  = (const float*)d_in[3];  // (2)
  float* out = (float*)d_out;

  unsigned long long* ws = (unsigned long long*)d_ws;        // TK_GRID*5 u64
  unsigned* cnt = (unsigned*)((char*)d_ws + TK_GRID * 5 * sizeof(unsigned long long));

  qa_logits_kernel<<<TOTAL / 4, 256, 0, stream>>>(X, mask, W, bqa, out, cnt);
  topk_kernel<<<TK_GRID, RPB, 0, stream>>>(out, out, ws, cnt);
}

// Round 11
// 34.718 us; speedup vs baseline: 1.0845x; 1.0845x over previous
//
#include <hip/hip_runtime.h>
#include <cfloat>

#define NEG_INF_F (-1e30f)

constexpr int BB = 8, SS = 4096, HH = 1024;
constexpr int TOTAL = BB * SS;   // 32768 rows
constexpr int MAXLEN = 30;
constexpr int RPB = 64;          // stage-1 rows per block
constexpr int TPR = 4;           // threads per row
constexpr int CPT = 8;           // candidates per thread (ceil(30/4))
constexpr int BLK_PER_B = SS / RPB;          // 64
constexpr int S1_GRID = BB * BLK_PER_B;      // 512

// ---------------- Kernel 1: QA-head GEMV + masking (proven ~20.5 us) ---------
// NOTE: plain __launch_bounds__(256) only — a min-waves hint caps VGPRs and
// serializes the 12 in-flight loads (R6/R8: 370 GB/s disaster).
__global__ __launch_bounds__(256) void qa_logits_kernel(
    const float* __restrict__ X,     // (B*S, H)
    const float* __restrict__ mask,  // (B*S)
    const float* __restrict__ W,     // (H, 2) row-major
    const float* __restrict__ bqa,   // (2)
    float* __restrict__ out) {       // [0,TOTAL): start, [TOTAL,2*TOTAL): end
  int row  = (int)((blockIdx.x * (size_t)blockDim.x + threadIdx.x) >> 6);
  int lane = threadIdx.x & 63;
  if (row >= TOTAL) return;
  const float* rp = X + (size_t)row * HH;
  float s0 = 0.f, s1 = 0.f;
#pragma unroll
  for (int k = 0; k < HH / 256; ++k) {
    int h = (k * 64 + lane) * 4;
    const float4 x   = *reinterpret_cast<const float4*>(rp + h);
    const float4 w01 = *reinterpret_cast<const float4*>(W + 2 * h);
    const float4 w23 = *reinterpret_cast<const float4*>(W + 2 * h + 4);
    s0 += x.x * w01.x + x.y * w01.z + x.z * w23.x + x.w * w23.z;
    s1 += x.x * w01.y + x.y * w01.w + x.z * w23.y + x.w * w23.w;
  }
#pragma unroll
  for (int off = 32; off > 0; off >>= 1) {
    s0 += __shfl_down(s0, off);
    s1 += __shfl_down(s1, off);
  }
  if (lane == 0) {
    float m = mask[row];
    float inv = 1.f - m;
    out[row]         = (s0 + bqa[0]) * m + inv * NEG_INF_F;
    out[TOTAL + row] = (s1 + bqa[1]) * m + inv * NEG_INF_F;
  }
}

// ---------- packed u64 key: (sortable-float << 32) | (~idx) ----------
// Higher key = higher value, then lower flat index (jax top_k tie-break).
// Validated end-to-end in rounds 8-10.
__device__ __forceinline__ unsigned long long pack_key(float v, unsigned idx) {
  unsigned u = __float_as_uint(v);
  u = (u & 0x80000000u) ? ~u : (u | 0x80000000u);
  return ((unsigned long long)u << 32) | (unsigned long long)(0xFFFFFFFFu - idx);
}

// Sorted-descending 5-key insert, early exit (keys unique, 0 = sentinel).
__device__ __forceinline__ void k5_insert(unsigned long long k[5], unsigned long long nk) {
  if (nk <= k[4]) return;
  k[4] = nk;
  unsigned long long t;
  if (k[4] > k[3]) { t = k[3]; k[3] = k[4]; k[4] = t; }
  if (k[3] > k[2]) { t = k[2]; k[2] = k[3]; k[3] = t; }
  if (k[2] > k[1]) { t = k[1]; k[1] = k[2]; k[2] = t; }
  if (k[1] > k[0]) { t = k[0]; k[0] = k[1]; k[1] = t; }
}

// Wave-wide top-5 via 5 argmax rounds on u64 keys; result same in all lanes.
__device__ __forceinline__ void wave_top5_u64(unsigned long long k[5],
                                              unsigned long long r[5]) {
#pragma unroll
  for (int q = 0; q < 5; ++q) {
    unsigned long long m = k[0];
    if (k[1] > m) m = k[1];
    if (k[2] > m) m = k[2];
    if (k[3] > m) m = k[3];
    if (k[4] > m) m = k[4];
#pragma unroll
    for (int off = 1; off < 64; off <<= 1) {
      unsigned long long o = __shfl_xor(m, off);
      if (o > m) m = o;
    }
    r[q] = m;
#pragma unroll
    for (int p = 0; p < 5; ++p)
      if (k[p] == m) k[p] = 0ull;  // keys unique; invalidate winner
  }
}

// ---------------- Stage 1: short-chain LDS-staged banded top-5 --------------
// 512 blocks x 256 threads (2 blocks/CU, 8 waves/CU). Block = 64 rows of one
// batch; 4 threads per row, 8 candidates each. Window values preloaded into
// registers via UNGUARDED LDS reads (invalid slots are NEG_INF by staging-pad
// or one cndmask) -> insert chain is 8 pure-VALU inserts.
__global__ __launch_bounds__(256) void topk_stage1(
    const float* __restrict__ logits,      // gemv output (start then end)
    unsigned long long* __restrict__ ws) { // (S1_GRID, 5) block top-5 keys
  const int b  = blockIdx.x / BLK_PER_B;
  const int rb = blockIdx.x % BLK_PER_B;
  const int i0 = rb * RPB;
  const int t  = (int)threadIdx.x;
  const int lane = t & 63;
  const int w = t >> 6;

  __shared__ float s_st[RPB];
  __shared__ float s_en[RPB + 32];  // 96 floats: window tail + NEG_INF pad
  __shared__ unsigned long long sk[4 * 5];

  const float* st = logits + (size_t)b * SS + i0;
  const float* en = logits + (size_t)(BB + b) * SS + i0;
  const int n_en = min(SS - i0, RPB + MAXLEN - 1);  // 93 (64 for last chunk)

  // stage: t<16 -> s_st (16 float4); t in [16,40) -> s_en (24 float4, 96 floats)
  if (t < 16) {
    *reinterpret_cast<float4*>(&s_st[t * 4]) =
        *reinterpret_cast<const float4*>(st + t * 4);
  } else if (t < 40) {
    int r = t - 16;
    if (r * 4 + 4 <= n_en)
      *reinterpret_cast<float4*>(&s_en[r * 4]) =
          *reinterpret_cast<const float4*>(en + r * 4);
    else
#pragma unroll
      for (int c = 0; c < 4; ++c)
        s_en[r * 4 + c] = (r * 4 + c < n_en) ? en[r * 4 + c] : NEG_INF_F;
  }
  __syncthreads();

  unsigned long long k5[5] = {0, 0, 0, 0, 0};
  const int lr = t >> 2;       // local row 0..63
  const int sub = t & 3;       // candidate slice
  const int i = i0 + lr;

  if (i >= 4) {
    float sv = s_st[lr];
    int c0 = sub * CPT;
    float e[CPT];
#pragma unroll
    for (int c = 0; c < CPT; ++c)  // unguarded LDS reads (max idx 94 < 96)
      e[c] = (c0 + c < MAXLEN) ? s_en[lr + c0 + c] : NEG_INF_F;
    unsigned base = (unsigned)(i * SS + i + c0);
#pragma unroll
    for (int c = 0; c < CPT; ++c) k5_insert(k5, pack_key(sv + e[c], base + c));
  } else if (i >= 1 && sub == 0) {  // spans (1,1),(2,2),(3,3)
    k5_insert(k5, pack_key(s_st[lr] + s_en[lr], (unsigned)(i * SS + i)));
  }

  unsigned long long r5[5];
  wave_top5_u64(k5, r5);
  if (lane == 0) {
#pragma unroll
    for (int q = 0; q < 5; ++q) sk[w * 5 + q] = r5[q];
  }
  __syncthreads();

  if (w == 0) {  // merge 4 waves * 5 = 20 keys -> block top-5
    unsigned long long m5[5] = {0, 0, 0, 0, 0};
    if (lane < 20) m5[0] = sk[lane];
    unsigned long long f5[5];
    wave_top5_u64(m5, f5);
    if (lane == 0) {
#pragma unroll
      for (int q = 0; q < 5; ++q) ws[blockIdx.x * 5 + q] = f5[q];
    }
  }
}

// ---------------- Stage 2: per-batch merge of 64 blocks * 5 = 320 keys ------
__global__ __launch_bounds__(64) void topk_stage2(
    const unsigned long long* __restrict__ ws,
    float* __restrict__ out) {
  const int b = blockIdx.x;
  const int lane = (int)threadIdx.x;
  const unsigned long long* src = ws + (size_t)b * BLK_PER_B * 5;  // 320 keys

  unsigned long long k5[5];
#pragma unroll
  for (int q = 0; q < 5; ++q) k5[q] = src[q * 64 + lane];  // exactly 5/lane

  unsigned long long r5[5];
  wave_top5_u64(k5, r5);

  if (lane == 0) {
    float* ts = out + 2 * (size_t)TOTAL;  // top_start region
    float* te = ts + BB * 5;              // top_end region
#pragma unroll
    for (int q = 0; q < 5; ++q) {
      unsigned idx = 0xFFFFFFFFu - (unsigned)(r5[q] & 0xFFFFFFFFull);
      ts[b * 5 + q] = (float)(idx >> 12);       // idx / S  (S=4096)
      te[b * 5 + q] = (float)(idx & (SS - 1));  // idx % S
    }
  }
}

extern "C" void kernel_launch(void* const* d_in, const int* in_sizes, int n_in,
                              void* d_out, int out_size, void* d_ws, size_t ws_size,
                              hipStream_t stream) {
  const float* X    = (const float*)d_in[0];  // (B,S,H)
  const float* mask = (const float*)d_in[1];  // (B,S)
  const float* W    = (const float*)d_in[2];  // (H,2)
  const float* bqa  = (const float*)d_in[3];  // (2)
  float* out = (float*)d_out;
  unsigned long long* ws = (unsigned long long*)d_ws;  // S1_GRID*5 u64 = 20 KB

  qa_logits_kernel<<<TOTAL / 4, 256, 0, stream>>>(X, mask, W, bqa, out);
  topk_stage1<<<S1_GRID, 256, 0, stream>>>(out, ws);
  topk_stage2<<<BB, 64, 0, stream>>>(ws, out);
}